// Round 10
// baseline (1085.113 us; speedup 1.0000x reference)
//
#include <hip/hip_runtime.h>
#include <hip/hip_bf16.h>
#include <hip/hip_fp8.h>

// ---------------------------------------------------------------------------
// GRACE contrastive loss, MI355X.
//  out = mean_k 0.5*(ln d1_k + ln d2_k) - 2*s12[k,k]
// With M=[n1;n2] (24576x256, fp8, pre-scaled), everything is row sums of
// exp2(M M^T) over upper-triangle 128x128 tiles (G symmetric), plus diag.
//
// R10: sym pipeline rebuild.
//  (a) per-nj accumulator (16 AGPR, was 64) + single 32KB full-K LDS buffer
//      -> ~156 regs/wave -> __launch_bounds__(256,3) -> 3 blocks/CU.
//  (b) register prefetch (8 x i32x4 per lane, coalesced) + swizzled
//      ds_write_b128, replacing global_load_lds: barrier drains are cheap
//      lgkm waits; global-load wait is mid-pipeline, covered by compute.
//  (c) col-sum atomics deferred one tile: issued at the START of the next
//      tile's compute (~1500cyc before the barrier that drains them).
//  Also: H stored bf16 (halves proj2->norm traffic).
// ---------------------------------------------------------------------------

#define NROWS 12288
#define TWO_N 24576
#define KDIM 256
#define BM 128
#define BN 128
#define BK 32
#define NTILES 192              /* 24576/128 */
#define CTILES 12               /* tiles per block; 18528/12 = 1544 blocks */
#define NBLK 1544
#define LOG2E 1.4426950408889634f
#define SIMSCALE 1.6986436f     /* sqrt(2*log2(e)); acc = (1/tau)*log2e*s */
#define LN2F 0.6931471805599453f

#if __has_builtin(__builtin_amdgcn_exp2f)
#define EXP2F(x) __builtin_amdgcn_exp2f(x)
#else
#define EXP2F(x) exp2f(x)
#endif

typedef __bf16 bf16x8 __attribute__((ext_vector_type(8)));
typedef __bf16 bf16x4v __attribute__((ext_vector_type(4)));
typedef float f32x4 __attribute__((ext_vector_type(4)));
typedef int i32x4 __attribute__((ext_vector_type(4)));
typedef int i32x8 __attribute__((ext_vector_type(8)));
typedef unsigned char uchar;

typedef const __attribute__((address_space(1))) void* gptr_t;
typedef __attribute__((address_space(3))) void* lptr_t;

// ======== legacy 128x128 bf16 GEMM core (proj1/proj2 only) ================
__device__ __forceinline__ void stage_slab(const __bf16* g, int row0, int kelem,
                                           __bf16* lds, int w, int l) {
#pragma unroll
  for (int t = 0; t < 2; ++t) {
    int chunk = w * 2 + t;
    int r = chunk * 16 + (l >> 2);
    int c = l & 3;
    int src = c ^ (r & 3);
    const __bf16* ga = g + (size_t)(row0 + r) * KDIM + kelem + src * 8;
    __bf16* la = lds + chunk * 512;
    __builtin_amdgcn_global_load_lds((gptr_t)ga, (lptr_t)la, 16, 0, 0);
  }
}

__device__ __forceinline__ bf16x8 read_frag(const __bf16* lds, int rowbase,
                                            int tile, int l) {
  int r = rowbase + tile * 16 + (l & 15);
  int q = l >> 4;
  int blk = q ^ (r & 3);
  return *(const bf16x8*)(lds + r * 32 + blk * 8);
}

__device__ __forceinline__ void gemm_tile_core(const __bf16* A, int arow0,
                                               const __bf16* B, int brow0,
                                               __bf16* As, __bf16* Bs,
                                               f32x4 (&acc)[4][4], int w, int l) {
  const int warow = (w >> 1) * 64;
  const int wbrow = (w & 1) * 64;
#pragma unroll
  for (int ks = 0; ks < KDIM / BK; ++ks) {
    __syncthreads();
    stage_slab(A, arow0, ks * BK, As, w, l);
    stage_slab(B, brow0, ks * BK, Bs, w, l);
    __syncthreads();
    bf16x8 aF[4], bF[4];
#pragma unroll
    for (int mi = 0; mi < 4; ++mi) aF[mi] = read_frag(As, warow, mi, l);
#pragma unroll
    for (int ni = 0; ni < 4; ++ni) bF[ni] = read_frag(Bs, wbrow, ni, l);
#pragma unroll
    for (int mi = 0; mi < 4; ++mi)
#pragma unroll
      for (int ni = 0; ni < 4; ++ni)
        acc[mi][ni] = __builtin_amdgcn_mfma_f32_16x16x32_bf16(
            aF[mi], bF[ni], acc[mi][ni], 0, 0, 0);
  }
}

// ---------------------------------------------------------------------------
// fused pair-cast: [0,n4) from a, [n4,2*n4) from b
__global__ void cast2_kernel(const float* __restrict__ a,
                             const float* __restrict__ b,
                             __bf16* __restrict__ da, __bf16* __restrict__ db,
                             int n4) {
  int i = blockIdx.x * blockDim.x + threadIdx.x;
  const float* s;
  __bf16* d;
  int j;
  if (i < n4) {
    s = a; d = da; j = i;
  } else {
    j = i - n4;
    if (j >= n4) return;
    s = b; d = db;
  }
  float4 v = *(const float4*)(s + (size_t)j * 4);
  bf16x4v o;
  o[0] = (__bf16)v.x; o[1] = (__bf16)v.y; o[2] = (__bf16)v.z; o[3] = (__bf16)v.w;
  *(bf16x4v*)(d + (size_t)j * 4) = o;
}

// T = ELU(Z @ W1^T + b1), stored bf16
__global__ __launch_bounds__(256, 2) void proj1_kernel(
    const __bf16* __restrict__ Zb, const __bf16* __restrict__ W1b,
    const float* __restrict__ b1, __bf16* __restrict__ Tb) {
  __shared__ __align__(16) __bf16 As[BM * BK];
  __shared__ __align__(16) __bf16 Bs[BN * BK];
  int w = threadIdx.x >> 6, l = threadIdx.x & 63;
  int i0 = blockIdx.x * BM, j0 = blockIdx.y * BN;
  int warow = (w >> 1) * 64, wbrow = (w & 1) * 64;
  f32x4 acc[4][4] = {};
  gemm_tile_core(Zb, i0, W1b, j0, As, Bs, acc, w, l);
  float bias[4];
#pragma unroll
  for (int ni = 0; ni < 4; ++ni) bias[ni] = b1[j0 + wbrow + ni * 16 + (l & 15)];
#pragma unroll
  for (int mi = 0; mi < 4; ++mi)
#pragma unroll
    for (int ni = 0; ni < 4; ++ni)
#pragma unroll
      for (int v = 0; v < 4; ++v) {
        int row = i0 + warow + mi * 16 + (l >> 4) * 4 + v;
        int col = j0 + wbrow + ni * 16 + (l & 15);
        float x = acc[mi][ni][v] + bias[ni];
        x = x > 0.f ? x : (EXP2F(x * LOG2E) - 1.f);  // ELU
        Tb[(size_t)row * KDIM + col] = (__bf16)x;
      }
}

// H = T @ W2^T + b2 (stored bf16), plus per-row sum of squares via atomics
__global__ __launch_bounds__(256, 2) void proj2_kernel(
    const __bf16* __restrict__ Tb, const __bf16* __restrict__ W2b,
    const float* __restrict__ b2, __bf16* __restrict__ Hb,
    float* __restrict__ SS) {
  __shared__ __align__(16) __bf16 As[BM * BK];
  __shared__ __align__(16) __bf16 Bs[BN * BK];
  int w = threadIdx.x >> 6, l = threadIdx.x & 63;
  int i0 = blockIdx.x * BM, j0 = blockIdx.y * BN;
  int warow = (w >> 1) * 64, wbrow = (w & 1) * 64;
  f32x4 acc[4][4] = {};
  gemm_tile_core(Tb, i0, W2b, j0, As, Bs, acc, w, l);
  float bias[4];
#pragma unroll
  for (int ni = 0; ni < 4; ++ni) bias[ni] = b2[j0 + wbrow + ni * 16 + (l & 15)];
  float ss[4][4] = {};
#pragma unroll
  for (int mi = 0; mi < 4; ++mi)
#pragma unroll
    for (int ni = 0; ni < 4; ++ni)
#pragma unroll
      for (int v = 0; v < 4; ++v) {
        int row = i0 + warow + mi * 16 + (l >> 4) * 4 + v;
        int col = j0 + wbrow + ni * 16 + (l & 15);
        float x = acc[mi][ni][v] + bias[ni];
        Hb[(size_t)row * KDIM + col] = (__bf16)x;
        ss[mi][v] += x * x;
      }
#pragma unroll
  for (int mi = 0; mi < 4; ++mi)
#pragma unroll
    for (int v = 0; v < 4; ++v) {
      float x = ss[mi][v];
      x += __shfl_xor(x, 1, 64);
      x += __shfl_xor(x, 2, 64);
      x += __shfl_xor(x, 4, 64);
      x += __shfl_xor(x, 8, 64);
      if ((l & 15) == 0)
        atomicAdd(&SS[i0 + warow + mi * 16 + (l >> 4) * 4 + v], x);
    }
}

// pack 4 floats -> 4 fp8 e4m3 bytes
__device__ __forceinline__ unsigned int pack4_fp8(float a, float b, float c,
                                                  float d) {
#if __has_builtin(__builtin_amdgcn_cvt_pk_fp8_f32)
  int v = 0;
  v = __builtin_amdgcn_cvt_pk_fp8_f32(a, b, v, false);
  v = __builtin_amdgcn_cvt_pk_fp8_f32(c, d, v, true);
  return (unsigned int)v;
#else
  __hip_fp8_e4m3 qa(a), qb(b), qc(c), qd(d);
  return (unsigned int)qa.__x | ((unsigned int)qb.__x << 8) |
         ((unsigned int)qc.__x << 16) | ((unsigned int)qd.__x << 24);
#endif
}

// Nq = fp8(Hb * rsqrt(SS[row]) * SIMSCALE) — 8 elements per thread.
__global__ void norm_kernel(const __bf16* __restrict__ Hb,
                            const float* __restrict__ SS,
                            uchar* __restrict__ Nq) {
  int i = blockIdx.x * blockDim.x + threadIdx.x;
  size_t idx = (size_t)i * 8;
  if (idx >= (size_t)TWO_N * KDIM) return;
  int row = (int)(idx >> 8);
  float inv = rsqrtf(SS[row]) * SIMSCALE;
  bf16x8 h = *(const bf16x8*)(Hb + idx);
  uint2 o;
  o.x = pack4_fp8((float)h[0] * inv, (float)h[1] * inv, (float)h[2] * inv,
                  (float)h[3] * inv);
  o.y = pack4_fp8((float)h[4] * inv, (float)h[5] * inv, (float)h[6] * inv,
                  (float)h[7] * inv);
  *(uint2*)(Nq + idx) = o;
}

// ======== R10 sym kernel ===================================================
// 1544 blocks x 256 thr, 12 upper-triangle tiles each. Single 32KB LDS
// buffer (full-K b-tile); next tile prefetched to registers during compute,
// ds_written at the tile boundary. Col-sum atomics deferred one tile.
__global__ __launch_bounds__(256, 3) void sym_kernel(
    const uchar* __restrict__ Nq, float* __restrict__ Rlow,
    float* __restrict__ Rhigh, float* __restrict__ Dsame,
    float* __restrict__ Dcross) {
  __shared__ __align__(16) uchar Bs[BM * KDIM];  // 32KB
  int tid = threadIdx.x;
  int w = tid >> 6, l = tid & 63;
  int q = l >> 4;
  int warow = (w >> 1) * 64;   // A rows of this wave within the a-block
  int wbcol = (w & 1) * 64;    // B cols of this wave within the b-block

  // --- locate first tile of this block in the flattened triangle ---
  int t0 = blockIdx.x * CTILES;
  auto rowoff = [](int a) { return a * NTILES - ((a * (a - 1)) >> 1); };
  int a = (int)((385.0f - sqrtf(148225.0f - 8.0f * (float)t0)) * 0.5f) - 1;
  if (a < 0) a = 0;
  while (rowoff(a + 1) <= t0) ++a;
  while (rowoff(a) > t0) --a;
  int b = a + (t0 - rowoff(a));

  // ---- register prefetch of a b-tile: 8 x i32x4 per lane (8KB/wave) ----
  i32x4 pf[8];
  auto load_pf = [&](int bt) {
#pragma unroll
    for (int t = 0; t < 8; ++t) {
      int r = w * 32 + t * 4 + (l >> 4);
      const uchar* ga = Nq + (size_t)(bt * BM + r) * KDIM + (l & 15) * 16;
      pf[t] = *(const i32x4*)ga;
    }
  };
  // swizzled LDS write: global block c of row r lands in slot c ^ (r&15)
  auto write_pf = [&]() {
#pragma unroll
    for (int t = 0; t < 8; ++t) {
      int r = w * 32 + t * 4 + (l >> 4);
      int slot = (l & 15) ^ (r & 15);
      *(i32x4*)(Bs + r * KDIM + slot * 16) = pf[t];
    }
  };

  // A fragments for the current a-block: aF[mi][hf], 64 VGPRs.
  i32x8 aF[4][2];
  auto load_aF = [&](int at) {
#pragma unroll
    for (int mi = 0; mi < 4; ++mi) {
      const uchar* ap =
          Nq + (size_t)(at * BM + warow + mi * 16 + (l & 15)) * KDIM + q * 32;
#pragma unroll
      for (int hf = 0; hf < 2; ++hf)
        aF[mi][hf] = *(const i32x8*)(ap + hf * 128);
    }
  };

  float rs[4][4] = {};  // row sums for current (a, half) run
  float csd[4];         // deferred col sums (previous tile)
  int bprev = -1;       // deferred col-sum target block (-1 = none)
  float* Rd = Rlow;     // deferred target half

  auto flush_rows = [&](int at, int hb) {
    float* R = hb ? Rhigh : Rlow;
#pragma unroll
    for (int mi = 0; mi < 4; ++mi)
#pragma unroll
      for (int v = 0; v < 4; ++v) {
        float x = rs[mi][v];
        x += __shfl_xor(x, 1, 64);
        x += __shfl_xor(x, 2, 64);
        x += __shfl_xor(x, 4, 64);
        x += __shfl_xor(x, 8, 64);
        if ((l & 15) == 0)
          atomicAdd(&R[at * BM + warow + mi * 16 + q * 4 + v], x);
        rs[mi][v] = 0.f;
      }
  };

  load_aF(a);
  load_pf(b);  // prefetch first b-tile into registers

#pragma unroll 1
  for (int t = 0; t < CTILES; ++t) {
    int na = a, nb = b + 1;
    if (nb == NTILES) { na = a + 1; nb = na; }

    __syncthreads();   // all waves done reading Bs (previous tile)
    write_pf();        // vmcnt wait for pf loads auto-inserted here
    __syncthreads();   // tile b visible in LDS (cheap lgkm drain)

    if (t + 1 < CTILES) load_pf(nb);  // prefetch next; waits at next write_pf

    // deferred col-sum flush for the PREVIOUS tile — atomics now have the
    // whole compute phase below to retire before the next barrier drain
    if (bprev >= 0) {
#pragma unroll
      for (int ni = 0; ni < 4; ++ni) {
        float x = csd[ni];
        x += __shfl_xor(x, 16, 64);
        x += __shfl_xor(x, 32, 64);
        if (l < 16) atomicAdd(&Rd[bprev * BM + wbcol + ni * 16 + l], x);
      }
    }

    bool diag = (a == b);
    bool cross = (b == a + NTILES / 2);
    int hb = (b >= NTILES / 2);
    float cs[4] = {};

    // ---- compute: per-nj full-K accumulator (16 AGPR live) ----
#pragma unroll
    for (int ni = 0; ni < 4; ++ni) {
      int row = wbcol + ni * 16 + (l & 15);
      const uchar* base = Bs + row * KDIM;
      f32x4 acc[4] = {};
#pragma unroll
      for (int hf = 0; hf < 2; ++hf) {
        int kb = hf * 8 + 2 * q;
        i32x4 lo = *(const i32x4*)(base + ((kb ^ (row & 15)) << 4));
        i32x4 hi = *(const i32x4*)(base + (((kb + 1) ^ (row & 15)) << 4));
        i32x8 bF = __builtin_shufflevector(lo, hi, 0, 1, 2, 3, 4, 5, 6, 7);
#pragma unroll
        for (int mi = 0; mi < 4; ++mi)
          acc[mi] = __builtin_amdgcn_mfma_scale_f32_16x16x128_f8f6f4(
              aF[mi][hf], bF, acc[mi], 0, 0, 0, 0x7F7F7F7F, 0, 0x7F7F7F7F);
      }
#pragma unroll
      for (int mi = 0; mi < 4; ++mi)
#pragma unroll
        for (int v = 0; v < 4; ++v) {
          float e = EXP2F(acc[mi][v]);
          rs[mi][v] += e;
          cs[ni] += e;
        }
      if (diag | cross) {  // wave-uniform, rare
        float* D = diag ? Dsame : Dcross;
#pragma unroll
        for (int mi = 0; mi < 4; ++mi)
#pragma unroll
          for (int v = 0; v < 4; ++v) {
            int li = warow + mi * 16 + q * 4 + v;
            int lj = wbcol + ni * 16 + (l & 15);
            if (li == lj) D[a * BM + li] = acc[mi][v];
          }
      }
    }

    // defer this tile's col flush to the next iteration
    if (!diag) {
      bprev = b;
      Rd = (a >= NTILES / 2) ? Rhigh : Rlow;
#pragma unroll
      for (int ni = 0; ni < 4; ++ni) csd[ni] = cs[ni];
    } else {
      bprev = -1;
    }

    // advance; flush row sums on a-change or half-change (rare atomics)
    if (t + 1 < CTILES) {
      int nhb = (nb >= NTILES / 2);
      if (na != a || nhb != hb) {
        flush_rows(a, hb);
        if (na != a) load_aF(na);
      }
      a = na;
      b = nb;
    } else {
      flush_rows(a, hb);
    }
  }

  // tail: last tile's deferred col flush
  if (bprev >= 0) {
#pragma unroll
    for (int ni = 0; ni < 4; ++ni) {
      float x = csd[ni];
      x += __shfl_xor(x, 16, 64);
      x += __shfl_xor(x, 32, 64);
      if (l < 16) atomicAdd(&Rd[bprev * BM + wbcol + ni * 16 + l], x);
    }
  }
}

// Dsame/Dcross hold acc = (1/tau)*log2e * s. exp(s/tau) = exp2(acc);
// -2*s = -ln2 * acc.
__global__ void finalize_kernel(const float* __restrict__ Rlow,
                                const float* __restrict__ Rhigh,
                                const float* __restrict__ Dsame,
                                const float* __restrict__ Dcross,
                                float* __restrict__ out) {
  __shared__ float red[256];
  float acc = 0.f;
  for (int k = threadIdx.x; k < NROWS; k += 256) {
    float d1 = Rlow[k] + Rhigh[k] - EXP2F(Dsame[k]);
    float d2 = Rhigh[NROWS + k] + Rlow[NROWS + k] - EXP2F(Dsame[NROWS + k]);
    acc += 0.5f * (logf(d1) + logf(d2)) - LN2F * Dcross[k];
  }
  red[threadIdx.x] = acc;
  __syncthreads();
  for (int s = 128; s > 0; s >>= 1) {
    if (threadIdx.x < s) red[threadIdx.x] += red[threadIdx.x + s];
    __syncthreads();
  }
  if (threadIdx.x == 0) out[0] = red[0] / (float)NROWS;
}

// ---------------------------------------------------------------------------
extern "C" void kernel_launch(void* const* d_in, const int* in_sizes, int n_in,
                              void* d_out, int out_size, void* d_ws,
                              size_t ws_size, hipStream_t stream) {
  const float* z1 = (const float*)d_in[0];
  const float* z2 = (const float*)d_in[1];
  const float* W1 = (const float*)d_in[2];
  const float* b1 = (const float*)d_in[3];
  const float* W2 = (const float*)d_in[4];
  const float* b2 = (const float*)d_in[5];
  float* out = (float*)d_out;

  char* ws = (char*)d_ws;
  size_t off = 0;
  auto alloc = [&](size_t bytes) -> void* {
    void* p = ws + off;
    off += (bytes + 255) & ~(size_t)255;
    return p;
  };
  __bf16* Zb   = (__bf16*)alloc((size_t)TWO_N * KDIM * 2); // reused as Nq
  __bf16* W1b  = (__bf16*)alloc((size_t)KDIM * KDIM * 2);
  __bf16* W2b  = (__bf16*)alloc((size_t)KDIM * KDIM * 2);
  __bf16* Tb   = (__bf16*)alloc((size_t)TWO_N * KDIM * 2);
  __bf16* Hb   = (__bf16*)alloc((size_t)TWO_N * KDIM * 2);
  float*  SS   = (float*)alloc((size_t)TWO_N * 4);
  float*  Rlow = (float*)alloc((size_t)TWO_N * 4);
  float*  Rhigh= (float*)alloc((size_t)TWO_N * 4);
  float*  Dsame= (float*)alloc((size_t)TWO_N * 4);
  float*  Dcross=(float*)alloc((size_t)NROWS * 4);
  uchar*  Nq = (uchar*)Zb;  // Zb dead after proj1; fp8 fits in its footprint

  hipMemsetAsync(SS, 0, (size_t)TWO_N * 4, stream);
  hipMemsetAsync(Rlow, 0, (size_t)TWO_N * 4, stream);
  hipMemsetAsync(Rhigh, 0, (size_t)TWO_N * 4, stream);

  int n4z = NROWS * KDIM / 4;   // 786432
  int n4w = KDIM * KDIM / 4;    // 16384
  cast2_kernel<<<(2 * n4z + 255) / 256, 256, 0, stream>>>(
      z1, z2, Zb, Zb + (size_t)NROWS * KDIM, n4z);
  cast2_kernel<<<(2 * n4w + 255) / 256, 256, 0, stream>>>(W1, W2, W1b, W2b,
                                                          n4w);

  proj1_kernel<<<dim3(TWO_N / BM, KDIM / BN), 256, 0, stream>>>(Zb, W1b, b1, Tb);
  proj2_kernel<<<dim3(TWO_N / BM, KDIM / BN), 256, 0, stream>>>(Tb, W2b, b2,
                                                                Hb, SS);

  int n8n = TWO_N * KDIM / 8;   // 786432
  norm_kernel<<<(n8n + 255) / 256, 256, 0, stream>>>(Hb, SS, Nq);

  sym_kernel<<<NBLK, 256, 0, stream>>>(Nq, Rlow, Rhigh, Dsame, Dcross);
  finalize_kernel<<<1, 256, 0, stream>>>(Rlow, Rhigh, Dsame, Dcross, out);
}

// Round 11
// 367.702 us; speedup vs baseline: 2.9511x; 2.9511x over previous
//
#include <hip/hip_runtime.h>
#include <hip/hip_bf16.h>
#include <hip/hip_fp8.h>

// ---------------------------------------------------------------------------
// GRACE contrastive loss, MI355X.
//  out = mean_k 0.5*(ln d1_k + ln d2_k) - 2*s12[k,k]
// With M=[n1;n2] (24576x256, fp8, pre-scaled), everything is row sums of
// exp2(M M^T) over upper-triangle 128x128 tiles (G symmetric), plus diag.
//
// R11: consolidation on the known-good R9 structure (sym 173.9us, VGPR 128,
// no spill). NEVER exceed (256,2) launch bounds here: R5/R7/R10 all spilled
// when the unified 256-reg budget was cut ((256,3)->170, (512,4)->128).
// Changes vs R9:
//  (a) col-sum atomics deferred one tile: issued at the START of the next
//      tile's compute (~3000cyc before the barrier vmcnt(0) drain that must
//      wait for them) instead of immediately before the barrier. +6 regs.
//  (b) H stored bf16 (halves proj2-write/norm-read traffic).
//  (c) SS computed inline in norm_kernel (32 lanes/row shuffle reduce):
//      drops SS buffer + memset dispatch + proj2 atomic epilogue.
// ---------------------------------------------------------------------------

#define NROWS 12288
#define TWO_N 24576
#define KDIM 256
#define BM 128
#define BN 128
#define BK 32
#define NTILES 192              /* 24576/128 */
#define CTILES 12               /* tiles per block; 18528/12 = 1544 blocks */
#define NBLK 1544
#define LOG2E 1.4426950408889634f
#define SIMSCALE 1.6986436f     /* sqrt(2*log2(e)); acc = (1/tau)*log2e*s */
#define LN2F 0.6931471805599453f

#if __has_builtin(__builtin_amdgcn_exp2f)
#define EXP2F(x) __builtin_amdgcn_exp2f(x)
#else
#define EXP2F(x) exp2f(x)
#endif

typedef __bf16 bf16x8 __attribute__((ext_vector_type(8)));
typedef __bf16 bf16x4v __attribute__((ext_vector_type(4)));
typedef float f32x4 __attribute__((ext_vector_type(4)));
typedef int i32x4 __attribute__((ext_vector_type(4)));
typedef int i32x8 __attribute__((ext_vector_type(8)));
typedef unsigned char uchar;

typedef const __attribute__((address_space(1))) void* gptr_t;
typedef __attribute__((address_space(3))) void* lptr_t;

// ======== legacy 128x128 bf16 GEMM core (proj1/proj2 only) ================
__device__ __forceinline__ void stage_slab(const __bf16* g, int row0, int kelem,
                                           __bf16* lds, int w, int l) {
#pragma unroll
  for (int t = 0; t < 2; ++t) {
    int chunk = w * 2 + t;
    int r = chunk * 16 + (l >> 2);
    int c = l & 3;
    int src = c ^ (r & 3);
    const __bf16* ga = g + (size_t)(row0 + r) * KDIM + kelem + src * 8;
    __bf16* la = lds + chunk * 512;
    __builtin_amdgcn_global_load_lds((gptr_t)ga, (lptr_t)la, 16, 0, 0);
  }
}

__device__ __forceinline__ bf16x8 read_frag(const __bf16* lds, int rowbase,
                                            int tile, int l) {
  int r = rowbase + tile * 16 + (l & 15);
  int q = l >> 4;
  int blk = q ^ (r & 3);
  return *(const bf16x8*)(lds + r * 32 + blk * 8);
}

__device__ __forceinline__ void gemm_tile_core(const __bf16* A, int arow0,
                                               const __bf16* B, int brow0,
                                               __bf16* As, __bf16* Bs,
                                               f32x4 (&acc)[4][4], int w, int l) {
  const int warow = (w >> 1) * 64;
  const int wbrow = (w & 1) * 64;
#pragma unroll
  for (int ks = 0; ks < KDIM / BK; ++ks) {
    __syncthreads();
    stage_slab(A, arow0, ks * BK, As, w, l);
    stage_slab(B, brow0, ks * BK, Bs, w, l);
    __syncthreads();
    bf16x8 aF[4], bF[4];
#pragma unroll
    for (int mi = 0; mi < 4; ++mi) aF[mi] = read_frag(As, warow, mi, l);
#pragma unroll
    for (int ni = 0; ni < 4; ++ni) bF[ni] = read_frag(Bs, wbrow, ni, l);
#pragma unroll
    for (int mi = 0; mi < 4; ++mi)
#pragma unroll
      for (int ni = 0; ni < 4; ++ni)
        acc[mi][ni] = __builtin_amdgcn_mfma_f32_16x16x32_bf16(
            aF[mi], bF[ni], acc[mi][ni], 0, 0, 0);
  }
}

// ---------------------------------------------------------------------------
// fused pair-cast: [0,n4) from a, [n4,2*n4) from b
__global__ void cast2_kernel(const float* __restrict__ a,
                             const float* __restrict__ b,
                             __bf16* __restrict__ da, __bf16* __restrict__ db,
                             int n4) {
  int i = blockIdx.x * blockDim.x + threadIdx.x;
  const float* s;
  __bf16* d;
  int j;
  if (i < n4) {
    s = a; d = da; j = i;
  } else {
    j = i - n4;
    if (j >= n4) return;
    s = b; d = db;
  }
  float4 v = *(const float4*)(s + (size_t)j * 4);
  bf16x4v o;
  o[0] = (__bf16)v.x; o[1] = (__bf16)v.y; o[2] = (__bf16)v.z; o[3] = (__bf16)v.w;
  *(bf16x4v*)(d + (size_t)j * 4) = o;
}

// T = ELU(Z @ W1^T + b1), stored bf16
__global__ __launch_bounds__(256, 2) void proj1_kernel(
    const __bf16* __restrict__ Zb, const __bf16* __restrict__ W1b,
    const float* __restrict__ b1, __bf16* __restrict__ Tb) {
  __shared__ __align__(16) __bf16 As[BM * BK];
  __shared__ __align__(16) __bf16 Bs[BN * BK];
  int w = threadIdx.x >> 6, l = threadIdx.x & 63;
  int i0 = blockIdx.x * BM, j0 = blockIdx.y * BN;
  int warow = (w >> 1) * 64, wbrow = (w & 1) * 64;
  f32x4 acc[4][4] = {};
  gemm_tile_core(Zb, i0, W1b, j0, As, Bs, acc, w, l);
  float bias[4];
#pragma unroll
  for (int ni = 0; ni < 4; ++ni) bias[ni] = b1[j0 + wbrow + ni * 16 + (l & 15)];
#pragma unroll
  for (int mi = 0; mi < 4; ++mi)
#pragma unroll
    for (int ni = 0; ni < 4; ++ni)
#pragma unroll
      for (int v = 0; v < 4; ++v) {
        int row = i0 + warow + mi * 16 + (l >> 4) * 4 + v;
        int col = j0 + wbrow + ni * 16 + (l & 15);
        float x = acc[mi][ni][v] + bias[ni];
        x = x > 0.f ? x : (EXP2F(x * LOG2E) - 1.f);  // ELU
        Tb[(size_t)row * KDIM + col] = (__bf16)x;
      }
}

// H = T @ W2^T + b2, stored bf16 (feeds fp8 quantization; bf16 is plenty)
__global__ __launch_bounds__(256, 2) void proj2_kernel(
    const __bf16* __restrict__ Tb, const __bf16* __restrict__ W2b,
    const float* __restrict__ b2, __bf16* __restrict__ Hb) {
  __shared__ __align__(16) __bf16 As[BM * BK];
  __shared__ __align__(16) __bf16 Bs[BN * BK];
  int w = threadIdx.x >> 6, l = threadIdx.x & 63;
  int i0 = blockIdx.x * BM, j0 = blockIdx.y * BN;
  int warow = (w >> 1) * 64, wbrow = (w & 1) * 64;
  f32x4 acc[4][4] = {};
  gemm_tile_core(Tb, i0, W2b, j0, As, Bs, acc, w, l);
  float bias[4];
#pragma unroll
  for (int ni = 0; ni < 4; ++ni) bias[ni] = b2[j0 + wbrow + ni * 16 + (l & 15)];
#pragma unroll
  for (int mi = 0; mi < 4; ++mi)
#pragma unroll
    for (int ni = 0; ni < 4; ++ni)
#pragma unroll
      for (int v = 0; v < 4; ++v) {
        int row = i0 + warow + mi * 16 + (l >> 4) * 4 + v;
        int col = j0 + wbrow + ni * 16 + (l & 15);
        Hb[(size_t)row * KDIM + col] = (__bf16)(acc[mi][ni][v] + bias[ni]);
      }
}

// pack 4 floats -> 4 fp8 e4m3 bytes
__device__ __forceinline__ unsigned int pack4_fp8(float a, float b, float c,
                                                  float d) {
#if __has_builtin(__builtin_amdgcn_cvt_pk_fp8_f32)
  int v = 0;
  v = __builtin_amdgcn_cvt_pk_fp8_f32(a, b, v, false);
  v = __builtin_amdgcn_cvt_pk_fp8_f32(c, d, v, true);
  return (unsigned int)v;
#else
  __hip_fp8_e4m3 qa(a), qb(b), qc(c), qd(d);
  return (unsigned int)qa.__x | ((unsigned int)qb.__x << 8) |
         ((unsigned int)qc.__x << 16) | ((unsigned int)qd.__x << 24);
#endif
}

// Nq = fp8(Hb * rsqrt(rowsum(Hb^2)) * SIMSCALE). 32 lanes per row: each lane
// holds 8 elems; sum-of-squares via 5 xor-shuffles (stay within 32-lane
// group); rsqrt; quantize. 8 rows per 256-thr block.
__global__ void norm_kernel(const __bf16* __restrict__ Hb,
                            uchar* __restrict__ Nq) {
  int tid = threadIdx.x;
  int row = blockIdx.x * 8 + (tid >> 5);
  int lane = tid & 31;
  size_t idx = (size_t)row * KDIM + lane * 8;
  bf16x8 h = *(const bf16x8*)(Hb + idx);
  float f[8];
  float ss = 0.f;
#pragma unroll
  for (int i = 0; i < 8; ++i) {
    f[i] = (float)h[i];
    ss += f[i] * f[i];
  }
  ss += __shfl_xor(ss, 1, 64);
  ss += __shfl_xor(ss, 2, 64);
  ss += __shfl_xor(ss, 4, 64);
  ss += __shfl_xor(ss, 8, 64);
  ss += __shfl_xor(ss, 16, 64);
  float inv = rsqrtf(ss) * SIMSCALE;
  uint2 o;
  o.x = pack4_fp8(f[0] * inv, f[1] * inv, f[2] * inv, f[3] * inv);
  o.y = pack4_fp8(f[4] * inv, f[5] * inv, f[6] * inv, f[7] * inv);
  *(uint2*)(Nq + idx) = o;
}

// ======== R11 sym kernel: R9 structure + deferred col atomics ==============
// 1544 blocks x 256 thr, 12 upper-triangle tiles each. Double-buffered
// global_load_lds staging (2x32KB). Tile t's col-sum atomics are issued at
// the start of tile t+1's compute so the barrier's vmcnt(0) drain never
// waits on them.
__global__ __launch_bounds__(256, 2) void sym_kernel(
    const uchar* __restrict__ Nq, float* __restrict__ Rlow,
    float* __restrict__ Rhigh, float* __restrict__ Dsame,
    float* __restrict__ Dcross) {
  __shared__ __align__(16) uchar Bs[2 * BM * KDIM];  // 2 x 32KB
  int tid = threadIdx.x;
  int w = tid >> 6, l = tid & 63;
  int q = l >> 4;
  int warow = (w >> 1) * 64;   // A rows of this wave within the a-block
  int wbcol = (w & 1) * 64;    // B cols of this wave within the b-block

  // --- locate first tile of this block in the flattened triangle ---
  int t0 = blockIdx.x * CTILES;
  auto rowoff = [](int a) { return a * NTILES - ((a * (a - 1)) >> 1); };
  int a = (int)((385.0f - sqrtf(148225.0f - 8.0f * (float)t0)) * 0.5f) - 1;
  if (a < 0) a = 0;
  while (rowoff(a + 1) <= t0) ++a;
  while (rowoff(a) > t0) --a;
  int b = a + (t0 - rowoff(a));

  // stage b-tile (128 rows x 256B) into buffer bi; source-side XOR swizzle.
  auto stage = [&](int bt, int bi) {
#pragma unroll
    for (int tt = 0; tt < 8; ++tt) {
      int ch = w * 8 + tt;           // wave-uniform chunk 0..31 (1KB each)
      int r = ch * 4 + (l >> 4);     // row 0..127
      int c = l & 15;                // dest 16B-block slot
      int src = c ^ (r & 15);        // global k-block landing in slot c
      const uchar* ga = Nq + (size_t)(bt * BM + r) * KDIM + src * 16;
      uchar* la = Bs + bi * (BM * KDIM) + ch * 1024;
      __builtin_amdgcn_global_load_lds((gptr_t)ga, (lptr_t)la, 16, 0, 0);
    }
  };

  // A fragments for the current a-block: aF[mi][hf], 64 VGPRs.
  i32x8 aF[4][2];
  auto load_aF = [&](int at) {
#pragma unroll
    for (int mi = 0; mi < 4; ++mi) {
      const uchar* ap =
          Nq + (size_t)(at * BM + warow + mi * 16 + (l & 15)) * KDIM + q * 32;
#pragma unroll
      for (int hf = 0; hf < 2; ++hf)
        aF[mi][hf] = *(const i32x8*)(ap + hf * 128);
    }
  };

  float rs[4][4] = {};  // row sums for current (a, half) run
  float csd[4];         // deferred col sums (previous tile)
  int bprev = -1;       // deferred col-sum target block (-1 = none)
  float* Rd = Rlow;     // deferred target half

  auto flush_rows = [&](int at, int hb) {
    float* R = hb ? Rhigh : Rlow;
#pragma unroll
    for (int mi = 0; mi < 4; ++mi)
#pragma unroll
      for (int v = 0; v < 4; ++v) {
        float x = rs[mi][v];
        x += __shfl_xor(x, 1, 64);
        x += __shfl_xor(x, 2, 64);
        x += __shfl_xor(x, 4, 64);
        x += __shfl_xor(x, 8, 64);
        if ((l & 15) == 0)
          atomicAdd(&R[at * BM + warow + mi * 16 + q * 4 + v], x);
        rs[mi][v] = 0.f;
      }
  };

  load_aF(a);
  stage(b, 0);

#pragma unroll 1
  for (int t = 0; t < CTILES; ++t) {
    int bi = t & 1;
    int na = a, nb = b + 1;
    if (nb == NTILES) { na = a + 1; nb = na; }

    __syncthreads();                       // stage(b,bi) done; prev readers done
    if (t + 1 < CTILES) stage(nb, bi ^ 1); // drains at next barrier

    // deferred col-sum flush for the PREVIOUS tile — the atomics now have
    // the whole MFMA phase below to retire before the next barrier drain
    if (bprev >= 0) {
#pragma unroll
      for (int ni = 0; ni < 4; ++ni) {
        float x = csd[ni];
        x += __shfl_xor(x, 16, 64);
        x += __shfl_xor(x, 32, 64);
        if (l < 16) atomicAdd(&Rd[bprev * BM + wbcol + ni * 16 + l], x);
      }
    }

    // ---- MFMA: full 128x128 tile, acc[mi][ni] ----
    f32x4 acc[4][4] = {};
#pragma unroll
    for (int hf = 0; hf < 2; ++hf) {
      i32x8 bF[4];
#pragma unroll
      for (int ni = 0; ni < 4; ++ni) {
        int row = wbcol + ni * 16 + (l & 15);
        const uchar* base = Bs + bi * (BM * KDIM) + row * KDIM;
        int kb = hf * 8 + 2 * q;
        i32x4 lo = *(const i32x4*)(base + ((kb ^ (row & 15)) << 4));
        i32x4 hi = *(const i32x4*)(base + (((kb + 1) ^ (row & 15)) << 4));
        bF[ni] = __builtin_shufflevector(lo, hi, 0, 1, 2, 3, 4, 5, 6, 7);
      }
#pragma unroll
      for (int mi = 0; mi < 4; ++mi)
#pragma unroll
        for (int ni = 0; ni < 4; ++ni)
          acc[mi][ni] = __builtin_amdgcn_mfma_scale_f32_16x16x128_f8f6f4(
              aF[mi][hf], bF[ni], acc[mi][ni], 0, 0, 0, 0x7F7F7F7F, 0,
              0x7F7F7F7F);
    }

    bool diag = (a == b);
    int hb = (b >= NTILES / 2);

    // ---- epilogue: exp once, add to row sums + per-tile col sums ----
    float cs[4] = {};
#pragma unroll
    for (int mi = 0; mi < 4; ++mi)
#pragma unroll
      for (int ni = 0; ni < 4; ++ni)
#pragma unroll
        for (int v = 0; v < 4; ++v) {
          float e = EXP2F(acc[mi][ni][v]);
          rs[mi][v] += e;
          cs[ni] += e;
        }

    // diagonal probes (wave-uniform branch; rare)
    if (diag | (b == a + NTILES / 2)) {
      float* D = diag ? Dsame : Dcross;
#pragma unroll
      for (int mi = 0; mi < 4; ++mi)
#pragma unroll
        for (int ni = 0; ni < 4; ++ni)
#pragma unroll
          for (int v = 0; v < 4; ++v) {
            int li = warow + mi * 16 + q * 4 + v;
            int lj = wbcol + ni * 16 + (l & 15);
            if (li == lj) D[a * BM + li] = acc[mi][ni][v];
          }
    }

    // defer this tile's col flush to the next iteration
    if (!diag) {
      bprev = b;
      Rd = (a >= NTILES / 2) ? Rhigh : Rlow;
#pragma unroll
      for (int ni = 0; ni < 4; ++ni) csd[ni] = cs[ni];
    } else {
      bprev = -1;
    }

    // ---- advance; flush row sums on a-change or half-change (rare) ----
    if (t + 1 < CTILES) {
      int nhb = (nb >= NTILES / 2);
      if (na != a || nhb != hb) {
        flush_rows(a, hb);
        if (na != a) load_aF(na);
      }
      a = na;
      b = nb;
    } else {
      flush_rows(a, hb);
    }
  }

  // tail: last tile's deferred col flush
  if (bprev >= 0) {
#pragma unroll
    for (int ni = 0; ni < 4; ++ni) {
      float x = csd[ni];
      x += __shfl_xor(x, 16, 64);
      x += __shfl_xor(x, 32, 64);
      if (l < 16) atomicAdd(&Rd[bprev * BM + wbcol + ni * 16 + l], x);
    }
  }
}

// Dsame/Dcross hold acc = (1/tau)*log2e * s. exp(s/tau) = exp2(acc);
// -2*s = -ln2 * acc.
__global__ void finalize_kernel(const float* __restrict__ Rlow,
                                const float* __restrict__ Rhigh,
                                const float* __restrict__ Dsame,
                                const float* __restrict__ Dcross,
                                float* __restrict__ out) {
  __shared__ float red[256];
  float acc = 0.f;
  for (int k = threadIdx.x; k < NROWS; k += 256) {
    float d1 = Rlow[k] + Rhigh[k] - EXP2F(Dsame[k]);
    float d2 = Rhigh[NROWS + k] + Rlow[NROWS + k] - EXP2F(Dsame[NROWS + k]);
    acc += 0.5f * (logf(d1) + logf(d2)) - LN2F * Dcross[k];
  }
  red[threadIdx.x] = acc;
  __syncthreads();
  for (int s = 128; s > 0; s >>= 1) {
    if (threadIdx.x < s) red[threadIdx.x] += red[threadIdx.x + s];
    __syncthreads();
  }
  if (threadIdx.x == 0) out[0] = red[0] / (float)NROWS;
}

// ---------------------------------------------------------------------------
extern "C" void kernel_launch(void* const* d_in, const int* in_sizes, int n_in,
                              void* d_out, int out_size, void* d_ws,
                              size_t ws_size, hipStream_t stream) {
  const float* z1 = (const float*)d_in[0];
  const float* z2 = (const float*)d_in[1];
  const float* W1 = (const float*)d_in[2];
  const float* b1 = (const float*)d_in[3];
  const float* W2 = (const float*)d_in[4];
  const float* b2 = (const float*)d_in[5];
  float* out = (float*)d_out;

  char* ws = (char*)d_ws;
  size_t off = 0;
  auto alloc = [&](size_t bytes) -> void* {
    void* p = ws + off;
    off += (bytes + 255) & ~(size_t)255;
    return p;
  };
  __bf16* Zb   = (__bf16*)alloc((size_t)TWO_N * KDIM * 2); // reused as Nq
  __bf16* W1b  = (__bf16*)alloc((size_t)KDIM * KDIM * 2);
  __bf16* W2b  = (__bf16*)alloc((size_t)KDIM * KDIM * 2);
  __bf16* Tb   = (__bf16*)alloc((size_t)TWO_N * KDIM * 2);
  __bf16* Hb   = (__bf16*)alloc((size_t)TWO_N * KDIM * 2);
  float*  Rlow = (float*)alloc((size_t)TWO_N * 4);
  float*  Rhigh= (float*)alloc((size_t)TWO_N * 4);
  float*  Dsame= (float*)alloc((size_t)TWO_N * 4);
  float*  Dcross=(float*)alloc((size_t)NROWS * 4);
  uchar*  Nq = (uchar*)Zb;  // Zb dead after proj1; fp8 fits in its footprint

  hipMemsetAsync(Rlow, 0, (size_t)TWO_N * 4, stream);
  hipMemsetAsync(Rhigh, 0, (size_t)TWO_N * 4, stream);

  int n4z = NROWS * KDIM / 4;   // 786432
  int n4w = KDIM * KDIM / 4;    // 16384
  cast2_kernel<<<(2 * n4z + 255) / 256, 256, 0, stream>>>(
      z1, z2, Zb, Zb + (size_t)NROWS * KDIM, n4z);
  cast2_kernel<<<(2 * n4w + 255) / 256, 256, 0, stream>>>(W1, W2, W1b, W2b,
                                                          n4w);

  proj1_kernel<<<dim3(TWO_N / BM, KDIM / BN), 256, 0, stream>>>(Zb, W1b, b1, Tb);
  proj2_kernel<<<dim3(TWO_N / BM, KDIM / BN), 256, 0, stream>>>(Tb, W2b, b2,
                                                                Hb);

  norm_kernel<<<TWO_N / 8, 256, 0, stream>>>(Hb, Nq);

  sym_kernel<<<NBLK, 256, 0, stream>>>(Nq, Rlow, Rhigh, Dsame, Dcross);
  finalize_kernel<<<1, 256, 0, stream>>>(Rlow, Rhigh, Dsame, Dcross, out);
}